// Round 3
// baseline (106.130 us; speedup 1.0000x reference)
//
#include <hip/hip_runtime.h>

// GraphAttention: B=4, S=512, H=8, DH=64, RD=64, DM=512
// Pipeline (5 launches):
//  K0 prep        : x->bf16; Wq/Wk/Wv->bf16; Wqr[(h,r),c] = sum_d Wr[d,r]*Wq[h*64+d,c]
//  K1 gemm128_qkv : 4 batches x @ {Wq,Wk,Wv,Wqr}^T, 128x128 tile, global_load_lds+swizzle,
//                   epilogue -> Qb/Kb (b,h,s,d), Vt (b,h,d,s), QRb (b,q,h,r), all bf16
//  K2 gemm128_c16 : Sqkb[b,h,q,k] = Qb @ Kb^T (batch=32, M=N=512, K=64, single stage)
//  K3 rel_fused   : s = (Sqk + QR.rel + q.br)/8 + mask; softmax -> P bf16 (rel read ONCE)
//  K4 gemm_nt     : out = P @ Vt^T (batch=32, M=512, N=64, K=512, f32 out)

typedef __attribute__((ext_vector_type(4))) float f32x4;
typedef __attribute__((ext_vector_type(8))) short s16x8;
typedef __attribute__((ext_vector_type(4))) unsigned short u16x4;
typedef __attribute__((ext_vector_type(8))) unsigned short u16x8;

typedef const __attribute__((address_space(1))) unsigned int* gas_ptr;
typedef __attribute__((address_space(3))) unsigned int* las_ptr;

__device__ __forceinline__ void gload16(const void* g, void* l) {
  __builtin_amdgcn_global_load_lds((gas_ptr)g, (las_ptr)l, 16, 0, 0);
}

__device__ __forceinline__ unsigned short f2bf(float f) {
  union { float f; unsigned int u; } x; x.f = f;
  return (unsigned short)((x.u + 0x7fffu + ((x.u >> 16) & 1u)) >> 16);  // RNE
}
__device__ __forceinline__ float bf2f(unsigned short u) {
  union { unsigned int u; float f; } x; x.u = ((unsigned int)u) << 16;
  return x.f;
}

// grid: 1024 (x cvt) + 768 (W cvt) + 1024 (Wqr) = 2816 blocks x 256
__global__ __launch_bounds__(256) void prep(
    const float* __restrict__ x, const float* __restrict__ Wq,
    const float* __restrict__ Wk, const float* __restrict__ Wv,
    const float* __restrict__ Wr, unsigned short* __restrict__ xb,
    unsigned short* __restrict__ Wb) {
  int blk = blockIdx.x, t = threadIdx.x;
  if (blk < 1024) {
    int i = (blk * 256 + t) * 4;
    f32x4 v = *(const f32x4*)(x + i);
    u16x4 u; u.x = f2bf(v.x); u.y = f2bf(v.y); u.z = f2bf(v.z); u.w = f2bf(v.w);
    *(u16x4*)(xb + i) = u;
  } else if (blk < 1792) {
    int i = ((blk - 1024) * 256 + t) * 4;  // [0, 786432)
    const float* src = (i < 262144) ? Wq : (i < 524288 ? Wk : Wv);
    f32x4 v = *(const f32x4*)(src + (i & 262143));
    u16x4 u; u.x = f2bf(v.x); u.y = f2bf(v.y); u.z = f2bf(v.z); u.w = f2bf(v.w);
    *(u16x4*)(Wb + i) = u;
  } else {
    int o = (blk - 1792) * 256 + t;  // [0, 262144)
    int c = o & 511, n = o >> 9, h = n >> 6, r = n & 63;
    float acc = 0.f;
#pragma unroll 8
    for (int d = 0; d < 64; ++d) acc += Wr[d * 64 + r] * Wq[(h * 64 + d) * 512 + c];
    Wb[3 * 262144 + o] = f2bf(acc);
  }
}

// ---- shared 128x128 BK=64 MFMA core --------------------------------------
// LDS layout: [128 rows][8 chunks of 16B]; chunk stored at cl = c ^ (row&7)
// (swizzle applied on global SOURCE; gload_lds dest stays linear; ds_read
//  applies the same XOR -> conflict-free reads, contiguous k-slices kept.)
#define G128_STAGE(MAT, SRC, LD, M0, K0)                                      \
  _Pragma("unroll") for (int is = 0; is < 4; ++is) {                          \
    int cb = (is * 4 + w) * 64;                                               \
    int fc = cb + lane;                                                       \
    int row = fc >> 3, cl = fc & 7;                                           \
    gload16(SRC + (long)(M0 + row) * LD + K0 + ((cl ^ (row & 7)) * 8),        \
            (char*)MAT + (size_t)fc * 16);                                    \
  }

#define G128_FRAGS(AF, BF)                                                    \
  _Pragma("unroll") for (int kk = 0; kk < 2; ++kk) {                          \
    _Pragma("unroll") for (int i = 0; i < 4; ++i) {                           \
      int ra = wm + 16 * i + fr;                                              \
      AF[kk][i] = *(const s16x8*)((const char*)As +                           \
                  ((size_t)ra * 8 + ((kk * 4 + g) ^ (ra & 7))) * 16);         \
      int rb = wn + 16 * i + fr;                                              \
      BF[kk][i] = *(const s16x8*)((const char*)Bs +                           \
                  ((size_t)rb * 8 + ((kk * 4 + g) ^ (rb & 7))) * 16);         \
    }                                                                         \
  }

// K1: C = xb @ Wb[z]^T, fused relayout epilogue. grid (16,4,4)
__global__ __launch_bounds__(256) void gemm128_qkv(
    const unsigned short* __restrict__ xb, const unsigned short* __restrict__ Wb,
    unsigned short* __restrict__ Qb, unsigned short* __restrict__ Kb,
    unsigned short* __restrict__ Vt, unsigned short* __restrict__ QRb) {
  int z = blockIdx.z;
  const unsigned short* A = xb;
  const unsigned short* Bm = Wb + (long)z * 262144;
  int m0 = blockIdx.x * 128, n0 = blockIdx.y * 128;
  __shared__ alignas(16) unsigned short As[128 * 64];
  __shared__ alignas(16) unsigned short Bs[128 * 64];
  int t = threadIdx.x, lane = t & 63, w = t >> 6;
  int wm = (w >> 1) * 64, wn = (w & 1) * 64;
  int fr = lane & 15, g = lane >> 4;
  f32x4 acc[4][4] = {};
  for (int k0 = 0; k0 < 512; k0 += 64) {
    __syncthreads();
    G128_STAGE(As, A, 512, m0, k0)
    G128_STAGE(Bs, Bm, 512, n0, k0)
    __syncthreads();
    s16x8 af[2][4], bf_[2][4];
    G128_FRAGS(af, bf_)
#pragma unroll
    for (int kk = 0; kk < 2; ++kk)
#pragma unroll
      for (int i = 0; i < 4; ++i)
#pragma unroll
        for (int j = 0; j < 4; ++j)
          acc[i][j] = __builtin_amdgcn_mfma_f32_16x16x32_bf16(af[kk][i], bf_[kk][j],
                                                              acc[i][j], 0, 0, 0);
  }
  int rbase = g * 4;
#pragma unroll
  for (int i = 0; i < 4; ++i)
#pragma unroll
    for (int j = 0; j < 4; ++j)
#pragma unroll
      for (int jj = 0; jj < 4; ++jj) {
        int row = m0 + wm + 16 * i + rbase + jj;  // m = b*512+s
        int cc  = n0 + wn + 16 * j + fr;          // n = h*64+d (or h*64+r)
        int b = row >> 9, s = row & 511, h = cc >> 6, d = cc & 63;
        unsigned short val = f2bf(acc[i][j][jj]);
        if (z == 0)      Qb[(((long)(b * 8 + h)) * 512 + s) * 64 + d] = val;
        else if (z == 1) Kb[(((long)(b * 8 + h)) * 512 + s) * 64 + d] = val;
        else if (z == 2) Vt[(((long)(b * 8 + h)) * 64 + d) * 512 + s] = val;
        else             QRb[(long)row * 512 + cc] = val;
      }
}

// K2: Sqkb[z] = A[z] @ B[z]^T, K=64 (single stage), bf16 out. grid (4,4,32)
__global__ __launch_bounds__(256) void gemm128_c16(
    const unsigned short* __restrict__ Ag, const unsigned short* __restrict__ Bg,
    unsigned short* __restrict__ Cb) {
  int z = blockIdx.z;
  const unsigned short* A = Ag + (long)z * 32768;
  const unsigned short* Bm = Bg + (long)z * 32768;
  long coff = (long)z * 262144;
  int m0 = blockIdx.x * 128, n0 = blockIdx.y * 128;
  __shared__ alignas(16) unsigned short As[128 * 64];
  __shared__ alignas(16) unsigned short Bs[128 * 64];
  int t = threadIdx.x, lane = t & 63, w = t >> 6;
  int wm = (w >> 1) * 64, wn = (w & 1) * 64;
  int fr = lane & 15, g = lane >> 4;
  f32x4 acc[4][4] = {};
  G128_STAGE(As, A, 64, m0, 0)
  G128_STAGE(Bs, Bm, 64, n0, 0)
  __syncthreads();
  s16x8 af[2][4], bf_[2][4];
  G128_FRAGS(af, bf_)
#pragma unroll
  for (int kk = 0; kk < 2; ++kk)
#pragma unroll
    for (int i = 0; i < 4; ++i)
#pragma unroll
      for (int j = 0; j < 4; ++j)
        acc[i][j] = __builtin_amdgcn_mfma_f32_16x16x32_bf16(af[kk][i], bf_[kk][j],
                                                            acc[i][j], 0, 0, 0);
  int rbase = g * 4;
#pragma unroll
  for (int i = 0; i < 4; ++i)
#pragma unroll
    for (int j = 0; j < 4; ++j)
#pragma unroll
      for (int jj = 0; jj < 4; ++jj) {
        long row = m0 + wm + 16 * i + rbase + jj;
        int cc   = n0 + wn + 16 * j + fr;
        Cb[coff + row * 512 + cc] = f2bf(acc[i][j][jj]);
      }
}

// K4: generic NT gemm 64x64 tile (PV): C = A @ B^T, f32 out.
__global__ __launch_bounds__(256) void gemm_nt(
    const unsigned short* __restrict__ A, int lda, long sA,
    const unsigned short* __restrict__ Bm, int ldb, long sB,
    float* __restrict__ Cv, int ldc, int subC, long sC1, long sC2, int K) {
  int z = blockIdx.z;
  A  += (long)z * sA;
  Bm += (long)z * sB;
  long coff = (long)(z / subC) * sC1 + (long)(z % subC) * sC2;
  int m0 = blockIdx.x * 64, n0 = blockIdx.y * 64;
  __shared__ alignas(16) unsigned short As[64][40];
  __shared__ alignas(16) unsigned short Bs[64][40];
  int t = threadIdx.x, lane = t & 63, w = t >> 6;
  int wm = (w >> 1) * 32, wn = (w & 1) * 32;
  int fr = lane & 15, fk = (lane >> 4) * 8;
  int sr = t >> 2, sc = (t & 3) * 8;
  f32x4 acc[2][2] = {};
  for (int k0 = 0; k0 < K; k0 += 32) {
    __syncthreads();
    *(u16x8*)&As[sr][sc] = *(const u16x8*)(A + (long)(m0 + sr) * lda + k0 + sc);
    *(u16x8*)&Bs[sr][sc] = *(const u16x8*)(Bm + (long)(n0 + sr) * ldb + k0 + sc);
    __syncthreads();
    s16x8 a0 = *(const s16x8*)&As[wm + fr][fk];
    s16x8 a1 = *(const s16x8*)&As[wm + 16 + fr][fk];
    s16x8 b0 = *(const s16x8*)&Bs[wn + fr][fk];
    s16x8 b1 = *(const s16x8*)&Bs[wn + 16 + fr][fk];
    acc[0][0] = __builtin_amdgcn_mfma_f32_16x16x32_bf16(a0, b0, acc[0][0], 0, 0, 0);
    acc[0][1] = __builtin_amdgcn_mfma_f32_16x16x32_bf16(a0, b1, acc[0][1], 0, 0, 0);
    acc[1][0] = __builtin_amdgcn_mfma_f32_16x16x32_bf16(a1, b0, acc[1][0], 0, 0, 0);
    acc[1][1] = __builtin_amdgcn_mfma_f32_16x16x32_bf16(a1, b1, acc[1][1], 0, 0, 0);
  }
  int rbase = (lane >> 4) * 4;
#pragma unroll
  for (int i = 0; i < 2; ++i)
#pragma unroll
    for (int j = 0; j < 2; ++j)
#pragma unroll
      for (int jj = 0; jj < 4; ++jj) {
        long row = m0 + wm + 16 * i + rbase + jj;
        int cc   = n0 + wn + 16 * j + fr;
        Cv[coff + row * ldc + cc] = acc[i][j][jj];
      }
}

// K3: per (b,q): s[h][k] = (Sqk + QR.rel + qb)*0.125 + mask ; softmax ; P bf16.
__global__ __launch_bounds__(256) void rel_fused(
    const float* __restrict__ rel, const int* __restrict__ graph,
    const unsigned short* __restrict__ Sqkb, const unsigned short* __restrict__ QRb,
    const unsigned short* __restrict__ Qb, const float* __restrict__ br,
    unsigned short* __restrict__ P) {
  int b = blockIdx.x >> 9, q = blockIdx.x & 511;
  __shared__ float s_lds[8][512];
  __shared__ unsigned short qr16[16][64];
  __shared__ float qb_lds[8];
  int t = threadIdx.x, lane = t & 63, w = t >> 6;

  if (t < 64) {
    u16x8 v = *(const u16x8*)(QRb + ((long)(b * 512 + q)) * 512 + t * 8);
    *(u16x8*)&qr16[t >> 3][(t & 7) * 8] = v;
  } else if (t < 128) {
    u16x8 zv = {};
    *(u16x8*)&qr16[8 + ((t - 64) >> 3)][((t - 64) & 7) * 8] = zv;
  }
  if (t >= 128 && t < 136) {
    int h = t - 128;
    const unsigned short* qrow = Qb + (((long)(b * 8 + h)) * 512 + q) * 64;
    float a = 0.f;
#pragma unroll 16
    for (int d = 0; d < 64; ++d) a += bf2f(qrow[d]) * br[d];
    qb_lds[h] = a;
  }
  __syncthreads();

  int fr = lane & 15, fk = (lane >> 4) * 8;
  s16x8 aq0 = *(const s16x8*)&qr16[fr][fk];
  s16x8 aq1 = *(const s16x8*)&qr16[fr][32 + fk];
  const float* rg = rel + ((long)(b * 512 + q)) * 32768;

  for (int c = 0; c < 8; ++c) {
    int krow = c * 64 + 16 * w + fr;
    const float* rp = rg + krow * 64;
    f32x4 r0 = *(const f32x4*)(rp + fk);
    f32x4 r1 = *(const f32x4*)(rp + fk + 4);
    f32x4 r2 = *(const f32x4*)(rp + 32 + fk);
    f32x4 r3 = *(const f32x4*)(rp + 32 + fk + 4);
    s16x8 b0, b1;
    b0[0] = (short)f2bf(r0.x); b0[1] = (short)f2bf(r0.y);
    b0[2] = (short)f2bf(r0.z); b0[3] = (short)f2bf(r0.w);
    b0[4] = (short)f2bf(r1.x); b0[5] = (short)f2bf(r1.y);
    b0[6] = (short)f2bf(r1.z); b0[7] = (short)f2bf(r1.w);
    b1[0] = (short)f2bf(r2.x); b1[1] = (short)f2bf(r2.y);
    b1[2] = (short)f2bf(r2.z); b1[3] = (short)f2bf(r2.w);
    b1[4] = (short)f2bf(r3.x); b1[5] = (short)f2bf(r3.y);
    b1[6] = (short)f2bf(r3.z); b1[7] = (short)f2bf(r3.w);
    f32x4 acc = {};
    acc = __builtin_amdgcn_mfma_f32_16x16x32_bf16(aq0, b0, acc, 0, 0, 0);
    acc = __builtin_amdgcn_mfma_f32_16x16x32_bf16(aq1, b1, acc, 0, 0, 0);
    if (lane < 32) {
      int k = c * 64 + 16 * w + fr;
      int hb = (lane >> 4) * 4;
#pragma unroll
      for (int j = 0; j < 4; ++j) s_lds[hb + j][k] = acc[j];
    }
  }
  __syncthreads();

  const int* grow = graph + ((long)(b * 512 + q)) * 512;
  for (int h = w; h < 8; h += 4) {
    const unsigned short* srow = Sqkb + (((long)(b * 8 + h)) * 512 + q) * 512;
    float qbh = qb_lds[h];
    float vals[8];
    float m = -3.0e38f;
#pragma unroll
    for (int i = 0; i < 8; ++i) {
      int k = lane + 64 * i;
      float msk = (1.0f - (float)grow[k]) * -1e9f;
      vals[i] = (s_lds[h][k] + bf2f(srow[k]) + qbh) * 0.125f + msk;
      m = fmaxf(m, vals[i]);
    }
#pragma unroll
    for (int off = 32; off >= 1; off >>= 1) m = fmaxf(m, __shfl_xor(m, off));
    float sum = 0.f;
#pragma unroll
    for (int i = 0; i < 8; ++i) { vals[i] = __expf(vals[i] - m); sum += vals[i]; }
#pragma unroll
    for (int off = 32; off >= 1; off >>= 1) sum += __shfl_xor(sum, off);
    float inv = 1.0f / sum;
    unsigned short* Pg = P + (((long)(b * 8 + h)) * 512 + q) * 512;
#pragma unroll
    for (int i = 0; i < 8; ++i) Pg[lane + 64 * i] = f2bf(vals[i] * inv);
  }
}

extern "C" void kernel_launch(void* const* d_in, const int* in_sizes, int n_in,
                              void* d_out, int out_size, void* d_ws, size_t ws_size,
                              hipStream_t stream) {
  const float* x     = (const float*)d_in[0];
  const int*   graph = (const int*)d_in[1];
  const float* rel   = (const float*)d_in[2];
  const float* Wq    = (const float*)d_in[3];
  const float* Wk    = (const float*)d_in[4];
  const float* Wv    = (const float*)d_in[5];
  const float* Wr    = (const float*)d_in[6];
  const float* br    = (const float*)d_in[7];
  float* out = (float*)d_out;

  char* wp = (char*)d_ws;
  unsigned short* xb  = (unsigned short*)wp; wp += (size_t)2 * 1048576;
  unsigned short* Wb  = (unsigned short*)wp; wp += (size_t)2 * 4 * 262144;
  unsigned short* Qb  = (unsigned short*)wp; wp += (size_t)2 * 1048576;
  unsigned short* Kb  = (unsigned short*)wp; wp += (size_t)2 * 1048576;
  unsigned short* Vt  = (unsigned short*)wp; wp += (size_t)2 * 1048576;
  unsigned short* QRb = (unsigned short*)wp; wp += (size_t)2 * 1048576;
  unsigned short* Sqkb = (unsigned short*)wp; wp += (size_t)2 * 8388608;
  unsigned short* P   = (unsigned short*)wp; wp += (size_t)2 * 8388608;

  prep<<<2816, 256, 0, stream>>>(x, Wq, Wk, Wv, Wr, xb, Wb);

  // Q/K/V/QR: M=2048, N=512, K=512, 4 batches
  gemm128_qkv<<<dim3(16, 4, 4), 256, 0, stream>>>(xb, Wb, Qb, Kb, Vt, QRb);

  // Sqk: M=N=512, K=64, 32 batches, bf16 out
  gemm128_c16<<<dim3(4, 4, 32), 256, 0, stream>>>(Qb, Kb, Sqkb);

  rel_fused<<<2048, 256, 0, stream>>>(rel, graph, Sqkb, QRb, Qb, br, P);

  // out = P @ Vt^T : M=512, N=64, K=512, 32 batches, f32 out
  gemm_nt<<<dim3(8, 1, 32), 256, 0, stream>>>(
      P, 512, 262144L, Vt, 512, 32768L, out, 512, 8, 262144L, 64L, 512);
}

// Round 4
// 79.886 us; speedup vs baseline: 1.3285x; 1.3285x over previous
//
#include <hip/hip_runtime.h>

// GraphAttention: B=4, S=512, H=8, DH=64, RD=64, DM=512
// Pipeline (5 launches):
//  K0 prep_w      : Wq/Wk/Wv->bf16; Wqr[(h,r),c] = sum_d Wr[d,r]*Wq[h*64+d,c] (bf16)
//  K1 gemm_qkv64  : 4 batches x(f32,reg-staged) @ {Wq,Wk,Wv,Wqr}^T, 64x64 tile BK=64,
//                   epilogue -> Qb/Kb (b,h,s,d), Vt (b,h,d,s), QRb (b,q,h,r), bf16
//  K2 gemm128_c16 : Sqkb[b,h,q,k] = Qb @ Kb^T (batch=32, M=N=512, K=64, single stage)
//  K3 rel_fused   : compact active k (graph==1), stream ONLY active rel rows (~128MB),
//                   s = (Sqk + QR.rel)/8 + mask; softmax -> P bf16.
//                   (q.br term cancels in softmax -- dropped entirely.)
//  K4 gemm_nt     : out = P @ Vt^T (batch=32, M=512, N=64, K=512, f32 out)

typedef __attribute__((ext_vector_type(4))) float f32x4;
typedef __attribute__((ext_vector_type(8))) short s16x8;
typedef __attribute__((ext_vector_type(4))) unsigned short u16x4;
typedef __attribute__((ext_vector_type(8))) unsigned short u16x8;

typedef const __attribute__((address_space(1))) unsigned int* gas_ptr;
typedef __attribute__((address_space(3))) unsigned int* las_ptr;

__device__ __forceinline__ void gload16(const void* g, void* l) {
  __builtin_amdgcn_global_load_lds((gas_ptr)g, (las_ptr)l, 16, 0, 0);
}

__device__ __forceinline__ unsigned short f2bf(float f) {
  union { float f; unsigned int u; } x; x.f = f;
  return (unsigned short)((x.u + 0x7fffu + ((x.u >> 16) & 1u)) >> 16);  // RNE
}
__device__ __forceinline__ float bf2f(unsigned short u) {
  union { unsigned int u; float f; } x; x.u = ((unsigned int)u) << 16;
  return x.f;
}

// grid: 768 (W cvt) + 1024 (Wqr) = 1792 blocks x 256
__global__ __launch_bounds__(256) void prep_w(
    const float* __restrict__ Wq, const float* __restrict__ Wk,
    const float* __restrict__ Wv, const float* __restrict__ Wr,
    unsigned short* __restrict__ Wb) {
  int blk = blockIdx.x, t = threadIdx.x;
  if (blk < 768) {
    int i = (blk * 256 + t) * 4;  // [0, 786432)
    const float* src = (i < 262144) ? Wq : (i < 524288 ? Wk : Wv);
    f32x4 v = *(const f32x4*)(src + (i & 262143));
    u16x4 u; u.x = f2bf(v.x); u.y = f2bf(v.y); u.z = f2bf(v.z); u.w = f2bf(v.w);
    *(u16x4*)(Wb + i) = u;
  } else {
    int o = (blk - 768) * 256 + t;  // [0, 262144)
    int c = o & 511, n = o >> 9, h = n >> 6, r = n & 63;
    float acc = 0.f;
#pragma unroll 8
    for (int d = 0; d < 64; ++d) acc += Wr[d * 64 + r] * Wq[(h * 64 + d) * 512 + c];
    Wb[3 * 262144 + o] = f2bf(acc);
  }
}

// K1: C = x @ Wb[z]^T, 64x64 tile, BK=64, reg-staged (A from f32). grid (32,8,4)
__global__ __launch_bounds__(256) void gemm_qkv64(
    const float* __restrict__ x, const unsigned short* __restrict__ Wb,
    unsigned short* __restrict__ Qb, unsigned short* __restrict__ Kb,
    unsigned short* __restrict__ Vt, unsigned short* __restrict__ QRb) {
  int z = blockIdx.z;
  const unsigned short* Bm = Wb + (long)z * 262144;
  int m0 = blockIdx.x * 64, n0 = blockIdx.y * 64;
  __shared__ alignas(16) unsigned short As[64][72];  // 144B row = 9x16B, aligned
  __shared__ alignas(16) unsigned short Bs[64][72];
  int t = threadIdx.x, lane = t & 63, w = t >> 6;
  int wm = (w >> 1) * 32, wn = (w & 1) * 32;
  int fr = lane & 15, fk = (lane >> 4) * 8;
  int sr = t >> 2, sc = (t & 3) * 16;
  f32x4 acc[2][2] = {};
  for (int k0 = 0; k0 < 512; k0 += 64) {
    __syncthreads();
    {
      const float* ap = x + (long)(m0 + sr) * 512 + k0 + sc;
      f32x4 v0 = *(const f32x4*)ap, v1 = *(const f32x4*)(ap + 4);
      f32x4 v2 = *(const f32x4*)(ap + 8), v3 = *(const f32x4*)(ap + 12);
      u16x8 u0, u1;
      u0[0] = f2bf(v0.x); u0[1] = f2bf(v0.y); u0[2] = f2bf(v0.z); u0[3] = f2bf(v0.w);
      u0[4] = f2bf(v1.x); u0[5] = f2bf(v1.y); u0[6] = f2bf(v1.z); u0[7] = f2bf(v1.w);
      u1[0] = f2bf(v2.x); u1[1] = f2bf(v2.y); u1[2] = f2bf(v2.z); u1[3] = f2bf(v2.w);
      u1[4] = f2bf(v3.x); u1[5] = f2bf(v3.y); u1[6] = f2bf(v3.z); u1[7] = f2bf(v3.w);
      *(u16x8*)&As[sr][sc] = u0;
      *(u16x8*)&As[sr][sc + 8] = u1;
      const unsigned short* bp = Bm + (long)(n0 + sr) * 512 + k0 + sc;
      *(u16x8*)&Bs[sr][sc] = *(const u16x8*)bp;
      *(u16x8*)&Bs[sr][sc + 8] = *(const u16x8*)(bp + 8);
    }
    __syncthreads();
#pragma unroll
    for (int kh = 0; kh < 2; ++kh) {
      s16x8 a0 = *(const s16x8*)&As[wm + fr][32 * kh + fk];
      s16x8 a1 = *(const s16x8*)&As[wm + 16 + fr][32 * kh + fk];
      s16x8 b0 = *(const s16x8*)&Bs[wn + fr][32 * kh + fk];
      s16x8 b1 = *(const s16x8*)&Bs[wn + 16 + fr][32 * kh + fk];
      acc[0][0] = __builtin_amdgcn_mfma_f32_16x16x32_bf16(a0, b0, acc[0][0], 0, 0, 0);
      acc[0][1] = __builtin_amdgcn_mfma_f32_16x16x32_bf16(a0, b1, acc[0][1], 0, 0, 0);
      acc[1][0] = __builtin_amdgcn_mfma_f32_16x16x32_bf16(a1, b0, acc[1][0], 0, 0, 0);
      acc[1][1] = __builtin_amdgcn_mfma_f32_16x16x32_bf16(a1, b1, acc[1][1], 0, 0, 0);
    }
  }
  int rbase = (lane >> 4) * 4;
#pragma unroll
  for (int i = 0; i < 2; ++i)
#pragma unroll
    for (int j = 0; j < 2; ++j)
#pragma unroll
      for (int jj = 0; jj < 4; ++jj) {
        int row = m0 + wm + 16 * i + rbase + jj;  // m = b*512+s
        int cc  = n0 + wn + 16 * j + fr;          // n = h*64+d (or h*64+r)
        int b = row >> 9, s = row & 511, h = cc >> 6, d = cc & 63;
        unsigned short val = f2bf(acc[i][j][jj]);
        if (z == 0)      Qb[(((long)(b * 8 + h)) * 512 + s) * 64 + d] = val;
        else if (z == 1) Kb[(((long)(b * 8 + h)) * 512 + s) * 64 + d] = val;
        else if (z == 2) Vt[(((long)(b * 8 + h)) * 64 + d) * 512 + s] = val;
        else             QRb[(long)row * 512 + cc] = val;
      }
}

// ---- 128x128 BK=64 core macros (used by gemm128_c16; verified r3) ---------
#define G128_STAGE(MAT, SRC, LD, M0, K0)                                      \
  _Pragma("unroll") for (int is = 0; is < 4; ++is) {                          \
    int cb = (is * 4 + w) * 64;                                               \
    int fc = cb + lane;                                                       \
    int row = fc >> 3, cl = fc & 7;                                           \
    gload16(SRC + (long)(M0 + row) * LD + K0 + ((cl ^ (row & 7)) * 8),        \
            (char*)MAT + (size_t)fc * 16);                                    \
  }

#define G128_FRAGS(AF, BF)                                                    \
  _Pragma("unroll") for (int kk = 0; kk < 2; ++kk) {                          \
    _Pragma("unroll") for (int i = 0; i < 4; ++i) {                           \
      int ra = wm + 16 * i + fr;                                              \
      AF[kk][i] = *(const s16x8*)((const char*)As +                           \
                  ((size_t)ra * 8 + ((kk * 4 + g) ^ (ra & 7))) * 16);         \
      int rb = wn + 16 * i + fr;                                              \
      BF[kk][i] = *(const s16x8*)((const char*)Bs +                           \
                  ((size_t)rb * 8 + ((kk * 4 + g) ^ (rb & 7))) * 16);         \
    }                                                                         \
  }

// K2: Sqkb[z] = A[z] @ B[z]^T, K=64 single stage, bf16 out. grid (4,4,32)
__global__ __launch_bounds__(256) void gemm128_c16(
    const unsigned short* __restrict__ Ag, const unsigned short* __restrict__ Bg,
    unsigned short* __restrict__ Cb) {
  int z = blockIdx.z;
  const unsigned short* A = Ag + (long)z * 32768;
  const unsigned short* Bm = Bg + (long)z * 32768;
  long coff = (long)z * 262144;
  int m0 = blockIdx.x * 128, n0 = blockIdx.y * 128;
  __shared__ alignas(16) unsigned short As[128 * 64];
  __shared__ alignas(16) unsigned short Bs[128 * 64];
  int t = threadIdx.x, lane = t & 63, w = t >> 6;
  int wm = (w >> 1) * 64, wn = (w & 1) * 64;
  int fr = lane & 15, g = lane >> 4;
  f32x4 acc[4][4] = {};
  G128_STAGE(As, A, 64, m0, 0)
  G128_STAGE(Bs, Bm, 64, n0, 0)
  __syncthreads();
  s16x8 af[2][4], bf_[2][4];
  G128_FRAGS(af, bf_)
#pragma unroll
  for (int kk = 0; kk < 2; ++kk)
#pragma unroll
    for (int i = 0; i < 4; ++i)
#pragma unroll
      for (int j = 0; j < 4; ++j)
        acc[i][j] = __builtin_amdgcn_mfma_f32_16x16x32_bf16(af[kk][i], bf_[kk][j],
                                                            acc[i][j], 0, 0, 0);
  int rbase = g * 4;
#pragma unroll
  for (int i = 0; i < 4; ++i)
#pragma unroll
    for (int j = 0; j < 4; ++j)
#pragma unroll
      for (int jj = 0; jj < 4; ++jj) {
        long row = m0 + wm + 16 * i + rbase + jj;
        int cc   = n0 + wn + 16 * j + fr;
        Cb[coff + row * 512 + cc] = f2bf(acc[i][j][jj]);
      }
}

// K4: generic NT gemm 64x64 tile (PV): C = A @ B^T, f32 out. (verified r2/r3)
__global__ __launch_bounds__(256) void gemm_nt(
    const unsigned short* __restrict__ A, int lda, long sA,
    const unsigned short* __restrict__ Bm, int ldb, long sB,
    float* __restrict__ Cv, int ldc, int subC, long sC1, long sC2, int K) {
  int z = blockIdx.z;
  A  += (long)z * sA;
  Bm += (long)z * sB;
  long coff = (long)(z / subC) * sC1 + (long)(z % subC) * sC2;
  int m0 = blockIdx.x * 64, n0 = blockIdx.y * 64;
  __shared__ alignas(16) unsigned short As[64][40];
  __shared__ alignas(16) unsigned short Bs[64][40];
  int t = threadIdx.x, lane = t & 63, w = t >> 6;
  int wm = (w >> 1) * 32, wn = (w & 1) * 32;
  int fr = lane & 15, fk = (lane >> 4) * 8;
  int sr = t >> 2, sc = (t & 3) * 8;
  f32x4 acc[2][2] = {};
  for (int k0 = 0; k0 < K; k0 += 32) {
    __syncthreads();
    *(u16x8*)&As[sr][sc] = *(const u16x8*)(A + (long)(m0 + sr) * lda + k0 + sc);
    *(u16x8*)&Bs[sr][sc] = *(const u16x8*)(Bm + (long)(n0 + sr) * ldb + k0 + sc);
    __syncthreads();
    s16x8 a0 = *(const s16x8*)&As[wm + fr][fk];
    s16x8 a1 = *(const s16x8*)&As[wm + 16 + fr][fk];
    s16x8 b0 = *(const s16x8*)&Bs[wn + fr][fk];
    s16x8 b1 = *(const s16x8*)&Bs[wn + 16 + fr][fk];
    acc[0][0] = __builtin_amdgcn_mfma_f32_16x16x32_bf16(a0, b0, acc[0][0], 0, 0, 0);
    acc[0][1] = __builtin_amdgcn_mfma_f32_16x16x32_bf16(a0, b1, acc[0][1], 0, 0, 0);
    acc[1][0] = __builtin_amdgcn_mfma_f32_16x16x32_bf16(a1, b0, acc[1][0], 0, 0, 0);
    acc[1][1] = __builtin_amdgcn_mfma_f32_16x16x32_bf16(a1, b1, acc[1][1], 0, 0, 0);
  }
  int rbase = (lane >> 4) * 4;
#pragma unroll
  for (int i = 0; i < 2; ++i)
#pragma unroll
    for (int j = 0; j < 2; ++j)
#pragma unroll
      for (int jj = 0; jj < 4; ++jj) {
        long row = m0 + wm + 16 * i + rbase + jj;
        int cc   = n0 + wn + 16 * j + fr;
        Cv[coff + row * ldc + cc] = acc[i][j][jj];
      }
}

// K3: per (b,q): compact active k; stream only active rel rows.
// s[h][k] = (Sqk + QR.rel)/8 + mask ; softmax ; P bf16.
__global__ __launch_bounds__(256) void rel_fused(
    const float* __restrict__ rel, const int* __restrict__ graph,
    const unsigned short* __restrict__ Sqkb, const unsigned short* __restrict__ QRb,
    unsigned short* __restrict__ P) {
  int b = blockIdx.x >> 9, q = blockIdx.x & 511;
  __shared__ float s_lds[8][512];            // 16KB rel-term scores (0 if masked)
  __shared__ unsigned short qr16[16][64];    // A operand: rows 0..7 QR, 8..15 zero
  __shared__ int idxL[512];
  __shared__ int cntL[8];
  int t = threadIdx.x, lane = t & 63, w = t >> 6;

  // zero rel-score buffer (masked columns stay 0)
#pragma unroll
  for (int i = 0; i < 4; ++i) {
    f32x4 zv = {};
    *(f32x4*)&s_lds[0][t * 4 + i * 1024] = zv;
  }
  // stage QR A-operand
  if (t < 64) {
    u16x8 v = *(const u16x8*)(QRb + ((long)(b * 512 + q)) * 512 + t * 8);
    *(u16x8*)&qr16[t >> 3][(t & 7) * 8] = v;
  } else if (t < 128) {
    u16x8 zv = {};
    *(u16x8*)&qr16[8 + ((t - 64) >> 3)][((t - 64) & 7) * 8] = zv;
  }
  // ballot-compact active k (order irrelevant)
  const int* grow = graph + ((long)(b * 512 + q)) * 512;
  int gA = grow[t], gB = grow[t + 256];
  unsigned long long mA = __ballot(gA != 0);
  unsigned long long mB = __ballot(gB != 0);
  unsigned long long below = (lane == 63) ? ~0ull : ((1ull << (lane + 1)) - 1);
  below >>= 1;  // bits strictly below lane
  int pA = __popcll(mA & below), pB = __popcll(mB & below);
  if (lane == 0) { cntL[w] = __popcll(mA); cntL[4 + w] = __popcll(mB); }
  __syncthreads();
  int base[8];
  int nact = 0;
#pragma unroll
  for (int g2 = 0; g2 < 8; ++g2) { base[g2] = nact; nact += cntL[g2]; }
  if (gA) idxL[base[w] + pA] = t;
  if (gB) idxL[base[4 + w] + pB] = t + 256;
  __syncthreads();

  int fr = lane & 15, fk = (lane >> 4) * 8;
  s16x8 aq0 = *(const s16x8*)&qr16[fr][fk];
  s16x8 aq1 = *(const s16x8*)&qr16[fr][32 + fk];
  const float* rg = rel + ((long)(b * 512 + q)) * 32768;
  int nchunk = (nact + 63) >> 6;

  for (int c = 0; c < nchunk; ++c) {
    int slot = c * 64 + 16 * w + fr;
    int krow = (slot < nact) ? idxL[slot] : 0;
    const float* rp = rg + krow * 64;
    f32x4 r0 = *(const f32x4*)(rp + fk);
    f32x4 r1 = *(const f32x4*)(rp + fk + 4);
    f32x4 r2 = *(const f32x4*)(rp + 32 + fk);
    f32x4 r3 = *(const f32x4*)(rp + 32 + fk + 4);
    s16x8 b0, b1;
    b0[0] = (short)f2bf(r0.x); b0[1] = (short)f2bf(r0.y);
    b0[2] = (short)f2bf(r0.z); b0[3] = (short)f2bf(r0.w);
    b0[4] = (short)f2bf(r1.x); b0[5] = (short)f2bf(r1.y);
    b0[6] = (short)f2bf(r1.z); b0[7] = (short)f2bf(r1.w);
    b1[0] = (short)f2bf(r2.x); b1[1] = (short)f2bf(r2.y);
    b1[2] = (short)f2bf(r2.z); b1[3] = (short)f2bf(r2.w);
    b1[4] = (short)f2bf(r3.x); b1[5] = (short)f2bf(r3.y);
    b1[6] = (short)f2bf(r3.z); b1[7] = (short)f2bf(r3.w);
    f32x4 acc = {};
    acc = __builtin_amdgcn_mfma_f32_16x16x32_bf16(aq0, b0, acc, 0, 0, 0);
    acc = __builtin_amdgcn_mfma_f32_16x16x32_bf16(aq1, b1, acc, 0, 0, 0);
    if (lane < 32 && slot < nact) {  // C rows(h): row=(lane>>4)*4+j, col = krow
      int hb = (lane >> 4) * 4;
#pragma unroll
      for (int j = 0; j < 4; ++j) s_lds[hb + j][krow] = acc[j];
    }
  }
  __syncthreads();

  for (int h = w; h < 8; h += 4) {  // wave w: rows h = w, w+4
    const unsigned short* srow = Sqkb + (((long)(b * 8 + h)) * 512 + q) * 512;
    float vals[8];
    float m = -3.0e38f;
#pragma unroll
    for (int i = 0; i < 8; ++i) {
      int k = lane + 64 * i;
      float msk = (1.0f - (float)grow[k]) * -1e9f;
      vals[i] = (s_lds[h][k] + bf2f(srow[k])) * 0.125f + msk;
      m = fmaxf(m, vals[i]);
    }
#pragma unroll
    for (int off = 32; off >= 1; off >>= 1) m = fmaxf(m, __shfl_xor(m, off));
    float sum = 0.f;
#pragma unroll
    for (int i = 0; i < 8; ++i) { vals[i] = __expf(vals[i] - m); sum += vals[i]; }
#pragma unroll
    for (int off = 32; off >= 1; off >>= 1) sum += __shfl_xor(sum, off);
    float inv = 1.0f / sum;
    unsigned short* Pg = P + (((long)(b * 8 + h)) * 512 + q) * 512;
#pragma unroll
    for (int i = 0; i < 8; ++i) Pg[lane + 64 * i] = f2bf(vals[i] * inv);
  }
}

extern "C" void kernel_launch(void* const* d_in, const int* in_sizes, int n_in,
                              void* d_out, int out_size, void* d_ws, size_t ws_size,
                              hipStream_t stream) {
  const float* x     = (const float*)d_in[0];
  const int*   graph = (const int*)d_in[1];
  const float* rel   = (const float*)d_in[2];
  const float* Wq    = (const float*)d_in[3];
  const float* Wk    = (const float*)d_in[4];
  const float* Wv    = (const float*)d_in[5];
  const float* Wr    = (const float*)d_in[6];
  float* out = (float*)d_out;

  char* wp = (char*)d_ws;
  unsigned short* Wb  = (unsigned short*)wp; wp += (size_t)2 * 4 * 262144;
  unsigned short* Qb  = (unsigned short*)wp; wp += (size_t)2 * 1048576;
  unsigned short* Kb  = (unsigned short*)wp; wp += (size_t)2 * 1048576;
  unsigned short* Vt  = (unsigned short*)wp; wp += (size_t)2 * 1048576;
  unsigned short* QRb = (unsigned short*)wp; wp += (size_t)2 * 1048576;
  unsigned short* Sqkb = (unsigned short*)wp; wp += (size_t)2 * 8388608;
  unsigned short* P   = (unsigned short*)wp; wp += (size_t)2 * 8388608;

  prep_w<<<1792, 256, 0, stream>>>(Wq, Wk, Wv, Wr, Wb);

  // Q/K/V/QR: M=2048, N=512, K=512, 4 batches, x read f32 + converted in-register
  gemm_qkv64<<<dim3(32, 8, 4), 256, 0, stream>>>(x, Wb, Qb, Kb, Vt, QRb);

  // Sqk: M=N=512, K=64, 32 batches, bf16 out
  gemm128_c16<<<dim3(4, 4, 32), 256, 0, stream>>>(Qb, Kb, Sqkb);

  rel_fused<<<2048, 256, 0, stream>>>(rel, graph, Sqkb, QRb, P);

  // out = P @ Vt^T : M=512, N=64, K=512, 32 batches, f32 out
  gemm_nt<<<dim3(8, 1, 32), 256, 0, stream>>>(
      P, 512, 262144L, Vt, 512, 32768L, out, 512, 8, 262144L, 64L, 512);
}

// Round 5
// 74.250 us; speedup vs baseline: 1.4294x; 1.0759x over previous
//
#include <hip/hip_runtime.h>

// GraphAttention: B=4, S=512, H=8, DH=64, RD=64, DM=512
// Pipeline (5 launches):
//  K0 prep        : x->bf16; Wq/Wk/Wv->bf16; Wqr[(h,r),c] = sum_d Wr[d,r]*Wq[h*64+d,c]
//  K1 gemm_qkv_g  : 4 batches xb @ {Wq,Wk,Wv,Wqr}^T, 64x64 tile BK=64,
//                   global_load_lds staging (swizzled), epilogue -> Qb/Kb/Vt/QRb bf16
//  K2 gemm128_c16 : Sqkb[b,h,q,k] = Qb @ Kb^T (batch=32, M=N=512, K=64, single stage)
//  K3 rel_fused   : compact active k (graph==1), stream ONLY active rel rows (~128MB),
//                   s_lds init -8e9 folds mask; s = (rel_score + Sqk)/8; softmax -> P bf16
//  K4 gemm_nt     : out = P @ Vt^T (batch=32, M=512, N=64, K=512, f32 out)

typedef __attribute__((ext_vector_type(4))) float f32x4;
typedef __attribute__((ext_vector_type(8))) short s16x8;
typedef __attribute__((ext_vector_type(4))) unsigned short u16x4;
typedef __attribute__((ext_vector_type(8))) unsigned short u16x8;

typedef const __attribute__((address_space(1))) unsigned int* gas_ptr;
typedef __attribute__((address_space(3))) unsigned int* las_ptr;

__device__ __forceinline__ void gload16(const void* g, void* l) {
  __builtin_amdgcn_global_load_lds((gas_ptr)g, (las_ptr)l, 16, 0, 0);
}

__device__ __forceinline__ unsigned short f2bf(float f) {
  union { float f; unsigned int u; } x; x.f = f;
  return (unsigned short)((x.u + 0x7fffu + ((x.u >> 16) & 1u)) >> 16);  // RNE
}
__device__ __forceinline__ float bf2f(unsigned short u) {
  union { unsigned int u; float f; } x; x.u = ((unsigned int)u) << 16;
  return x.f;
}

// grid: 1024 (x cvt) + 768 (W cvt) + 1024 (Wqr) = 2816 blocks x 256
__global__ __launch_bounds__(256) void prep(
    const float* __restrict__ x, const float* __restrict__ Wq,
    const float* __restrict__ Wk, const float* __restrict__ Wv,
    const float* __restrict__ Wr, unsigned short* __restrict__ xb,
    unsigned short* __restrict__ Wb) {
  int blk = blockIdx.x, t = threadIdx.x;
  if (blk < 1024) {
    int i = (blk * 256 + t) * 4;
    f32x4 v = *(const f32x4*)(x + i);
    u16x4 u; u.x = f2bf(v.x); u.y = f2bf(v.y); u.z = f2bf(v.z); u.w = f2bf(v.w);
    *(u16x4*)(xb + i) = u;
  } else if (blk < 1792) {
    int i = ((blk - 1024) * 256 + t) * 4;  // [0, 786432)
    const float* src = (i < 262144) ? Wq : (i < 524288 ? Wk : Wv);
    f32x4 v = *(const f32x4*)(src + (i & 262143));
    u16x4 u; u.x = f2bf(v.x); u.y = f2bf(v.y); u.z = f2bf(v.z); u.w = f2bf(v.w);
    *(u16x4*)(Wb + i) = u;
  } else {
    int o = (blk - 1792) * 256 + t;  // [0, 262144)
    int c = o & 511, n = o >> 9, h = n >> 6, r = n & 63;
    float acc = 0.f;
#pragma unroll 8
    for (int d = 0; d < 64; ++d) acc += Wr[d * 64 + r] * Wq[(h * 64 + d) * 512 + c];
    Wb[3 * 262144 + o] = f2bf(acc);
  }
}

// ---- swizzled gload_lds staging (rule 21: linear LDS dest, inverse-swz src,
//      swz ds_read). Layout: [rows][8 chunks of 16B], chunk c at c^(row&7). ----
// 64 rows (64x64 bf16 tile): 512 chunks, 2 per thread.
#define G64_STAGE(MAT, SRC, LD, M0, K0)                                       \
  _Pragma("unroll") for (int is = 0; is < 2; ++is) {                          \
    int fc = is * 256 + w * 64 + lane;                                        \
    int row = fc >> 3, cl = fc & 7;                                           \
    gload16(SRC + (long)(M0 + row) * LD + K0 + ((cl ^ (row & 7)) * 8),        \
            (char*)MAT + (size_t)fc * 16);                                    \
  }
// 128 rows (128x64 bf16 tile): 1024 chunks, 4 per thread.
#define G128_STAGE(MAT, SRC, LD, M0, K0)                                      \
  _Pragma("unroll") for (int is = 0; is < 4; ++is) {                          \
    int fc = (is * 4 + w) * 64 + lane;                                        \
    int row = fc >> 3, cl = fc & 7;                                           \
    gload16(SRC + (long)(M0 + row) * LD + K0 + ((cl ^ (row & 7)) * 8),        \
            (char*)MAT + (size_t)fc * 16);                                    \
  }

#define G128_FRAGS(AF, BF)                                                    \
  _Pragma("unroll") for (int kk = 0; kk < 2; ++kk) {                          \
    _Pragma("unroll") for (int i = 0; i < 4; ++i) {                           \
      int ra = wm + 16 * i + fr;                                              \
      AF[kk][i] = *(const s16x8*)((const char*)As +                           \
                  ((size_t)ra * 8 + ((kk * 4 + g) ^ (ra & 7))) * 16);         \
      int rb = wn + 16 * i + fr;                                              \
      BF[kk][i] = *(const s16x8*)((const char*)Bs +                           \
                  ((size_t)rb * 8 + ((kk * 4 + g) ^ (rb & 7))) * 16);         \
    }                                                                         \
  }

// K1: C = xb @ Wb[z]^T, 64x64 tile, BK=64, gload_lds staging. grid (32,8,4)
__global__ __launch_bounds__(256) void gemm_qkv_g(
    const unsigned short* __restrict__ xb, const unsigned short* __restrict__ Wb,
    unsigned short* __restrict__ Qb, unsigned short* __restrict__ Kb,
    unsigned short* __restrict__ Vt, unsigned short* __restrict__ QRb) {
  int z = blockIdx.z;
  const unsigned short* Bm = Wb + (long)z * 262144;
  int m0 = blockIdx.x * 64, n0 = blockIdx.y * 64;
  __shared__ alignas(16) unsigned short As[64 * 64];
  __shared__ alignas(16) unsigned short Bs[64 * 64];
  int t = threadIdx.x, lane = t & 63, w = t >> 6;
  int wm = (w >> 1) * 32, wn = (w & 1) * 32;
  int fr = lane & 15, g = lane >> 4;
  f32x4 acc[2][2] = {};
  for (int k0 = 0; k0 < 512; k0 += 64) {
    __syncthreads();
    G64_STAGE(As, xb, 512, m0, k0)
    G64_STAGE(Bs, Bm, 512, n0, k0)
    __syncthreads();
#pragma unroll
    for (int kh = 0; kh < 2; ++kh) {
      s16x8 a0, a1, b0, b1;
      {
        int ra = wm + fr;
        a0 = *(const s16x8*)((const char*)As + ((size_t)ra * 8 + ((kh * 4 + g) ^ (ra & 7))) * 16);
        int ra1 = wm + 16 + fr;
        a1 = *(const s16x8*)((const char*)As + ((size_t)ra1 * 8 + ((kh * 4 + g) ^ (ra1 & 7))) * 16);
        int rb = wn + fr;
        b0 = *(const s16x8*)((const char*)Bs + ((size_t)rb * 8 + ((kh * 4 + g) ^ (rb & 7))) * 16);
        int rb1 = wn + 16 + fr;
        b1 = *(const s16x8*)((const char*)Bs + ((size_t)rb1 * 8 + ((kh * 4 + g) ^ (rb1 & 7))) * 16);
      }
      acc[0][0] = __builtin_amdgcn_mfma_f32_16x16x32_bf16(a0, b0, acc[0][0], 0, 0, 0);
      acc[0][1] = __builtin_amdgcn_mfma_f32_16x16x32_bf16(a0, b1, acc[0][1], 0, 0, 0);
      acc[1][0] = __builtin_amdgcn_mfma_f32_16x16x32_bf16(a1, b0, acc[1][0], 0, 0, 0);
      acc[1][1] = __builtin_amdgcn_mfma_f32_16x16x32_bf16(a1, b1, acc[1][1], 0, 0, 0);
    }
  }
  int rbase = g * 4;
#pragma unroll
  for (int i = 0; i < 2; ++i)
#pragma unroll
    for (int j = 0; j < 2; ++j)
#pragma unroll
      for (int jj = 0; jj < 4; ++jj) {
        int row = m0 + wm + 16 * i + rbase + jj;  // m = b*512+s
        int cc  = n0 + wn + 16 * j + fr;          // n = h*64+d (or h*64+r)
        int b = row >> 9, s = row & 511, h = cc >> 6, d = cc & 63;
        unsigned short val = f2bf(acc[i][j][jj]);
        if (z == 0)      Qb[(((long)(b * 8 + h)) * 512 + s) * 64 + d] = val;
        else if (z == 1) Kb[(((long)(b * 8 + h)) * 512 + s) * 64 + d] = val;
        else if (z == 2) Vt[(((long)(b * 8 + h)) * 64 + d) * 512 + s] = val;
        else             QRb[(long)row * 512 + cc] = val;
      }
}

// K2: Sqkb[z] = A[z] @ B[z]^T, K=64 single stage, bf16 out. grid (4,4,32)
__global__ __launch_bounds__(256) void gemm128_c16(
    const unsigned short* __restrict__ Ag, const unsigned short* __restrict__ Bg,
    unsigned short* __restrict__ Cb) {
  int z = blockIdx.z;
  const unsigned short* A = Ag + (long)z * 32768;
  const unsigned short* Bm = Bg + (long)z * 32768;
  long coff = (long)z * 262144;
  int m0 = blockIdx.x * 128, n0 = blockIdx.y * 128;
  __shared__ alignas(16) unsigned short As[128 * 64];
  __shared__ alignas(16) unsigned short Bs[128 * 64];
  int t = threadIdx.x, lane = t & 63, w = t >> 6;
  int wm = (w >> 1) * 64, wn = (w & 1) * 64;
  int fr = lane & 15, g = lane >> 4;
  f32x4 acc[4][4] = {};
  G128_STAGE(As, A, 64, m0, 0)
  G128_STAGE(Bs, Bm, 64, n0, 0)
  __syncthreads();
  s16x8 af[2][4], bf_[2][4];
  G128_FRAGS(af, bf_)
#pragma unroll
  for (int kk = 0; kk < 2; ++kk)
#pragma unroll
    for (int i = 0; i < 4; ++i)
#pragma unroll
      for (int j = 0; j < 4; ++j)
        acc[i][j] = __builtin_amdgcn_mfma_f32_16x16x32_bf16(af[kk][i], bf_[kk][j],
                                                            acc[i][j], 0, 0, 0);
  int rbase = g * 4;
#pragma unroll
  for (int i = 0; i < 4; ++i)
#pragma unroll
    for (int j = 0; j < 4; ++j)
#pragma unroll
      for (int jj = 0; jj < 4; ++jj) {
        long row = m0 + wm + 16 * i + rbase + jj;
        int cc   = n0 + wn + 16 * j + fr;
        Cb[coff + row * 512 + cc] = f2bf(acc[i][j][jj]);
      }
}

// K4: generic NT gemm 64x64 tile (PV): C = A @ B^T, f32 out. (verified r2-r4)
__global__ __launch_bounds__(256) void gemm_nt(
    const unsigned short* __restrict__ A, int lda, long sA,
    const unsigned short* __restrict__ Bm, int ldb, long sB,
    float* __restrict__ Cv, int ldc, int subC, long sC1, long sC2, int K) {
  int z = blockIdx.z;
  A  += (long)z * sA;
  Bm += (long)z * sB;
  long coff = (long)(z / subC) * sC1 + (long)(z % subC) * sC2;
  int m0 = blockIdx.x * 64, n0 = blockIdx.y * 64;
  __shared__ alignas(16) unsigned short As[64][40];
  __shared__ alignas(16) unsigned short Bs[64][40];
  int t = threadIdx.x, lane = t & 63, w = t >> 6;
  int wm = (w >> 1) * 32, wn = (w & 1) * 32;
  int fr = lane & 15, fk = (lane >> 4) * 8;
  int sr = t >> 2, sc = (t & 3) * 8;
  f32x4 acc[2][2] = {};
  for (int k0 = 0; k0 < K; k0 += 32) {
    __syncthreads();
    *(u16x8*)&As[sr][sc] = *(const u16x8*)(A + (long)(m0 + sr) * lda + k0 + sc);
    *(u16x8*)&Bs[sr][sc] = *(const u16x8*)(Bm + (long)(n0 + sr) * ldb + k0 + sc);
    __syncthreads();
    s16x8 a0 = *(const s16x8*)&As[wm + fr][fk];
    s16x8 a1 = *(const s16x8*)&As[wm + 16 + fr][fk];
    s16x8 b0 = *(const s16x8*)&Bs[wn + fr][fk];
    s16x8 b1 = *(const s16x8*)&Bs[wn + 16 + fr][fk];
    acc[0][0] = __builtin_amdgcn_mfma_f32_16x16x32_bf16(a0, b0, acc[0][0], 0, 0, 0);
    acc[0][1] = __builtin_amdgcn_mfma_f32_16x16x32_bf16(a0, b1, acc[0][1], 0, 0, 0);
    acc[1][0] = __builtin_amdgcn_mfma_f32_16x16x32_bf16(a1, b0, acc[1][0], 0, 0, 0);
    acc[1][1] = __builtin_amdgcn_mfma_f32_16x16x32_bf16(a1, b1, acc[1][1], 0, 0, 0);
  }
  int rbase = (lane >> 4) * 4;
#pragma unroll
  for (int i = 0; i < 2; ++i)
#pragma unroll
    for (int j = 0; j < 2; ++j)
#pragma unroll
      for (int jj = 0; jj < 4; ++jj) {
        long row = m0 + wm + 16 * i + rbase + jj;
        int cc   = n0 + wn + 16 * j + fr;
        Cv[coff + row * ldc + cc] = acc[i][j][jj];
      }
}

// K3: per (b,q): compact active k; stream only active rel rows.
// s_lds init -8e9 encodes mask; s = (s_lds + Sqk)/8 ; softmax ; P bf16.
__global__ __launch_bounds__(256) void rel_fused(
    const float* __restrict__ rel, const int* __restrict__ graph,
    const unsigned short* __restrict__ Sqkb, const unsigned short* __restrict__ QRb,
    unsigned short* __restrict__ P) {
  int b = blockIdx.x >> 9, q = blockIdx.x & 511;
  __shared__ float s_lds[8][512];            // rel scores; -8e9 where masked
  __shared__ unsigned short qr16[16][64];    // A operand: rows 0..7 QR, 8..15 zero
  __shared__ int idxL[512];
  __shared__ int cntL[8];
  int t = threadIdx.x, lane = t & 63, w = t >> 6;

  // init rel-score buffer to -8e9 (masked cols keep it -> logit ~ -1e9)
#pragma unroll
  for (int i = 0; i < 4; ++i) {
    f32x4 mv = {-8e9f, -8e9f, -8e9f, -8e9f};
    *(f32x4*)&s_lds[0][t * 4 + i * 1024] = mv;
  }
  // stage QR A-operand
  if (t < 64) {
    u16x8 v = *(const u16x8*)(QRb + ((long)(b * 512 + q)) * 512 + t * 8);
    *(u16x8*)&qr16[t >> 3][(t & 7) * 8] = v;
  } else if (t < 128) {
    u16x8 zv = {};
    *(u16x8*)&qr16[8 + ((t - 64) >> 3)][((t - 64) & 7) * 8] = zv;
  }
  // ballot-compact active k (order irrelevant)
  const int* grow = graph + ((long)(b * 512 + q)) * 512;
  int gA = grow[t], gB = grow[t + 256];
  unsigned long long mA = __ballot(gA != 0);
  unsigned long long mB = __ballot(gB != 0);
  unsigned long long below = (lane == 63) ? ~0ull : ((1ull << (lane + 1)) - 1);
  below >>= 1;  // bits strictly below lane
  int pA = __popcll(mA & below), pB = __popcll(mB & below);
  if (lane == 0) { cntL[w] = __popcll(mA); cntL[4 + w] = __popcll(mB); }
  __syncthreads();
  int base[8];
  int nact = 0;
#pragma unroll
  for (int g2 = 0; g2 < 8; ++g2) { base[g2] = nact; nact += cntL[g2]; }
  if (gA) idxL[base[w] + pA] = t;
  if (gB) idxL[base[4 + w] + pB] = t + 256;
  __syncthreads();

  int fr = lane & 15, fk = (lane >> 4) * 8;
  s16x8 aq0 = *(const s16x8*)&qr16[fr][fk];
  s16x8 aq1 = *(const s16x8*)&qr16[fr][32 + fk];
  const float* rg = rel + ((long)(b * 512 + q)) * 32768;
  int nchunk = (nact + 63) >> 6;

  for (int c = 0; c < nchunk; ++c) {
    int slot = c * 64 + 16 * w + fr;
    int krow = (slot < nact) ? idxL[slot] : 0;
    const float* rp = rg + krow * 64;
    f32x4 r0 = *(const f32x4*)(rp + fk);
    f32x4 r1 = *(const f32x4*)(rp + fk + 4);
    f32x4 r2 = *(const f32x4*)(rp + 32 + fk);
    f32x4 r3 = *(const f32x4*)(rp + 32 + fk + 4);
    s16x8 b0, b1;
    b0[0] = (short)f2bf(r0.x); b0[1] = (short)f2bf(r0.y);
    b0[2] = (short)f2bf(r0.z); b0[3] = (short)f2bf(r0.w);
    b0[4] = (short)f2bf(r1.x); b0[5] = (short)f2bf(r1.y);
    b0[6] = (short)f2bf(r1.z); b0[7] = (short)f2bf(r1.w);
    b1[0] = (short)f2bf(r2.x); b1[1] = (short)f2bf(r2.y);
    b1[2] = (short)f2bf(r2.z); b1[3] = (short)f2bf(r2.w);
    b1[4] = (short)f2bf(r3.x); b1[5] = (short)f2bf(r3.y);
    b1[6] = (short)f2bf(r3.z); b1[7] = (short)f2bf(r3.w);
    f32x4 acc = {};
    acc = __builtin_amdgcn_mfma_f32_16x16x32_bf16(aq0, b0, acc, 0, 0, 0);
    acc = __builtin_amdgcn_mfma_f32_16x16x32_bf16(aq1, b1, acc, 0, 0, 0);
    if (lane < 32 && slot < nact) {  // C rows(h): row=(lane>>4)*4+j, col = krow
      int hb = (lane >> 4) * 4;
#pragma unroll
      for (int j = 0; j < 4; ++j) s_lds[hb + j][krow] = acc[j];
    }
  }
  __syncthreads();

  for (int h = w; h < 8; h += 4) {  // wave w: rows h = w, w+4
    const unsigned short* srow = Sqkb + (((long)(b * 8 + h)) * 512 + q) * 512;
    float vals[8];
    float m = -3.0e38f;
#pragma unroll
    for (int i = 0; i < 8; ++i) {
      int k = lane + 64 * i;
      vals[i] = (s_lds[h][k] + bf2f(srow[k])) * 0.125f;
      m = fmaxf(m, vals[i]);
    }
#pragma unroll
    for (int off = 32; off >= 1; off >>= 1) m = fmaxf(m, __shfl_xor(m, off));
    float sum = 0.f;
#pragma unroll
    for (int i = 0; i < 8; ++i) { vals[i] = __expf(vals[i] - m); sum += vals[i]; }
#pragma unroll
    for (int off = 32; off >= 1; off >>= 1) sum += __shfl_xor(sum, off);
    float inv = 1.0f / sum;
    unsigned short* Pg = P + (((long)(b * 8 + h)) * 512 + q) * 512;
#pragma unroll
    for (int i = 0; i < 8; ++i) Pg[lane + 64 * i] = f2bf(vals[i] * inv);
  }
}

extern "C" void kernel_launch(void* const* d_in, const int* in_sizes, int n_in,
                              void* d_out, int out_size, void* d_ws, size_t ws_size,
                              hipStream_t stream) {
  const float* x     = (const float*)d_in[0];
  const int*   graph = (const int*)d_in[1];
  const float* rel   = (const float*)d_in[2];
  const float* Wq    = (const float*)d_in[3];
  const float* Wk    = (const float*)d_in[4];
  const float* Wv    = (const float*)d_in[5];
  const float* Wr    = (const float*)d_in[6];
  float* out = (float*)d_out;

  char* wp = (char*)d_ws;
  unsigned short* xb  = (unsigned short*)wp; wp += (size_t)2 * 1048576;
  unsigned short* Wb  = (unsigned short*)wp; wp += (size_t)2 * 4 * 262144;
  unsigned short* Qb  = (unsigned short*)wp; wp += (size_t)2 * 1048576;
  unsigned short* Kb  = (unsigned short*)wp; wp += (size_t)2 * 1048576;
  unsigned short* Vt  = (unsigned short*)wp; wp += (size_t)2 * 1048576;
  unsigned short* QRb = (unsigned short*)wp; wp += (size_t)2 * 1048576;
  unsigned short* Sqkb = (unsigned short*)wp; wp += (size_t)2 * 8388608;
  unsigned short* P   = (unsigned short*)wp; wp += (size_t)2 * 8388608;

  prep<<<2816, 256, 0, stream>>>(x, Wq, Wk, Wv, Wr, xb, Wb);

  // Q/K/V/QR: M=2048, N=512, K=512, 4 batches, gload_lds staging
  gemm_qkv_g<<<dim3(32, 8, 4), 256, 0, stream>>>(xb, Wb, Qb, Kb, Vt, QRb);

  // Sqk: M=N=512, K=64, 32 batches, bf16 out
  gemm128_c16<<<dim3(4, 4, 32), 256, 0, stream>>>(Qb, Kb, Sqkb);

  rel_fused<<<2048, 256, 0, stream>>>(rel, graph, Sqkb, QRb, P);

  // out = P @ Vt^T : M=512, N=64, K=512, 32 batches, f32 out
  gemm_nt<<<dim3(8, 1, 32), 256, 0, stream>>>(
      P, 512, 262144L, Vt, 512, 32768L, out, 512, 8, 262144L, 64L, 512);
}

// Round 6
// 71.501 us; speedup vs baseline: 1.4843x; 1.0384x over previous
//
#include <hip/hip_runtime.h>

// GraphAttention: B=4, S=512, H=8, DH=64, RD=64, DM=512
// Pipeline (5 launches):
//  K0 prep        : x->bf16; Wq/Wk/Wv->bf16; Wqr[(h,r),c] = sum_d Wr[d,r]*Wq[h*64+d,c]
//  K1 gemm_qkv_g  : 4 batches xb @ {Wq,Wk,Wv,Wqr}^T, 64x64 tile BK=128,
//                   global_load_lds staging (swizzled), epilogue -> Qb/Kb/Vt/QRb bf16
//  K2 gemm128_c16 : Sqkb[b,h,q,k] = Qb @ Kb^T (batch=32, M=N=512, K=64, single stage)
//  K3 rel_fused   : compact active k; stream ONLY active rel rows (~128MB), 2-deep
//                   load pipeline; hoisted Sqk operands; softmax -> P bf16
//  K4 gemm_pv     : out = P @ Vt^T (batch=32, M=512 in 32-tiles, N=64, BK=64, f32 out)

typedef __attribute__((ext_vector_type(4))) float f32x4;
typedef __attribute__((ext_vector_type(8))) short s16x8;
typedef __attribute__((ext_vector_type(4))) unsigned short u16x4;
typedef __attribute__((ext_vector_type(8))) unsigned short u16x8;

typedef const __attribute__((address_space(1))) unsigned int* gas_ptr;
typedef __attribute__((address_space(3))) unsigned int* las_ptr;

__device__ __forceinline__ void gload16(const void* g, void* l) {
  __builtin_amdgcn_global_load_lds((gas_ptr)g, (las_ptr)l, 16, 0, 0);
}

__device__ __forceinline__ unsigned short f2bf(float f) {
  union { float f; unsigned int u; } x; x.f = f;
  return (unsigned short)((x.u + 0x7fffu + ((x.u >> 16) & 1u)) >> 16);  // RNE
}
__device__ __forceinline__ float bf2f(unsigned short u) {
  union { unsigned int u; float f; } x; x.u = ((unsigned int)u) << 16;
  return x.f;
}

// grid: 1024 (x cvt) + 768 (W cvt) + 1024 (Wqr) = 2816 blocks x 256
__global__ __launch_bounds__(256) void prep(
    const float* __restrict__ x, const float* __restrict__ Wq,
    const float* __restrict__ Wk, const float* __restrict__ Wv,
    const float* __restrict__ Wr, unsigned short* __restrict__ xb,
    unsigned short* __restrict__ Wb) {
  int blk = blockIdx.x, t = threadIdx.x;
  if (blk < 1024) {
    int i = (blk * 256 + t) * 4;
    f32x4 v = *(const f32x4*)(x + i);
    u16x4 u; u.x = f2bf(v.x); u.y = f2bf(v.y); u.z = f2bf(v.z); u.w = f2bf(v.w);
    *(u16x4*)(xb + i) = u;
  } else if (blk < 1792) {
    int i = ((blk - 1024) * 256 + t) * 4;  // [0, 786432)
    const float* src = (i < 262144) ? Wq : (i < 524288 ? Wk : Wv);
    f32x4 v = *(const f32x4*)(src + (i & 262143));
    u16x4 u; u.x = f2bf(v.x); u.y = f2bf(v.y); u.z = f2bf(v.z); u.w = f2bf(v.w);
    *(u16x4*)(Wb + i) = u;
  } else {
    int o = (blk - 1792) * 256 + t;  // [0, 262144)
    int c = o & 511, n = o >> 9, h = n >> 6, r = n & 63;
    float acc = 0.f;
#pragma unroll 8
    for (int d = 0; d < 64; ++d) acc += Wr[d * 64 + r] * Wq[(h * 64 + d) * 512 + c];
    Wb[3 * 262144 + o] = f2bf(acc);
  }
}

// ---- swizzled gload_lds staging (rule 21: linear LDS dest, inverse-swz src,
//      swz ds_read). Layout: [rows][chunks of 16B], chunk c at c^(row&7). ----
// 64 rows x BK=128 (16 chunks/row): 1024 chunks, 4 per thread.
#define G64K128_STAGE(MAT, SRC, LD, M0, K0)                                   \
  _Pragma("unroll") for (int is = 0; is < 4; ++is) {                          \
    int fc = is * 256 + t;                                                    \
    int row = fc >> 4, cl = fc & 15;                                          \
    gload16(SRC + (long)(M0 + row) * LD + K0 + ((cl ^ (row & 7)) * 8),        \
            (char*)MAT + (size_t)fc * 16);                                    \
  }
// 128 rows x BK=64 (8 chunks/row): 1024 chunks, 4 per thread.
#define G128_STAGE(MAT, SRC, LD, M0, K0)                                      \
  _Pragma("unroll") for (int is = 0; is < 4; ++is) {                          \
    int fc = is * 256 + t;                                                    \
    int row = fc >> 3, cl = fc & 7;                                           \
    gload16(SRC + (long)(M0 + row) * LD + K0 + ((cl ^ (row & 7)) * 8),        \
            (char*)MAT + (size_t)fc * 16);                                    \
  }

#define G128_FRAGS(AF, BF)                                                    \
  _Pragma("unroll") for (int kk = 0; kk < 2; ++kk) {                          \
    _Pragma("unroll") for (int i = 0; i < 4; ++i) {                           \
      int ra = wm + 16 * i + fr;                                              \
      AF[kk][i] = *(const s16x8*)((const char*)As +                           \
                  ((size_t)ra * 8 + ((kk * 4 + g) ^ (ra & 7))) * 16);         \
      int rb = wn + 16 * i + fr;                                              \
      BF[kk][i] = *(const s16x8*)((const char*)Bs +                           \
                  ((size_t)rb * 8 + ((kk * 4 + g) ^ (rb & 7))) * 16);         \
    }                                                                         \
  }

// K1: C = xb @ Wb[z]^T, 64x64 tile, BK=128, gload_lds staging. grid (32,8,4)
__global__ __launch_bounds__(256) void gemm_qkv_g(
    const unsigned short* __restrict__ xb, const unsigned short* __restrict__ Wb,
    unsigned short* __restrict__ Qb, unsigned short* __restrict__ Kb,
    unsigned short* __restrict__ Vt, unsigned short* __restrict__ QRb) {
  int z = blockIdx.z;
  const unsigned short* Bm = Wb + (long)z * 262144;
  int m0 = blockIdx.x * 64, n0 = blockIdx.y * 64;
  __shared__ alignas(16) unsigned short As[64 * 128];  // 16KB
  __shared__ alignas(16) unsigned short Bs[64 * 128];  // 16KB
  int t = threadIdx.x, lane = t & 63, w = t >> 6;
  int wm = (w >> 1) * 32, wn = (w & 1) * 32;
  int fr = lane & 15, g = lane >> 4;
  f32x4 acc[2][2] = {};
  for (int k0 = 0; k0 < 512; k0 += 128) {
    __syncthreads();
    G64K128_STAGE(As, xb, 512, m0, k0)
    G64K128_STAGE(Bs, Bm, 512, n0, k0)
    __syncthreads();
#pragma unroll
    for (int kh = 0; kh < 4; ++kh) {
      s16x8 a0, a1, b0, b1;
      {
        int ra = wm + fr;
        a0 = *(const s16x8*)((const char*)As + ((size_t)ra * 16 + ((kh * 4 + g) ^ (ra & 7))) * 16);
        int ra1 = wm + 16 + fr;
        a1 = *(const s16x8*)((const char*)As + ((size_t)ra1 * 16 + ((kh * 4 + g) ^ (ra1 & 7))) * 16);
        int rb = wn + fr;
        b0 = *(const s16x8*)((const char*)Bs + ((size_t)rb * 16 + ((kh * 4 + g) ^ (rb & 7))) * 16);
        int rb1 = wn + 16 + fr;
        b1 = *(const s16x8*)((const char*)Bs + ((size_t)rb1 * 16 + ((kh * 4 + g) ^ (rb1 & 7))) * 16);
      }
      acc[0][0] = __builtin_amdgcn_mfma_f32_16x16x32_bf16(a0, b0, acc[0][0], 0, 0, 0);
      acc[0][1] = __builtin_amdgcn_mfma_f32_16x16x32_bf16(a0, b1, acc[0][1], 0, 0, 0);
      acc[1][0] = __builtin_amdgcn_mfma_f32_16x16x32_bf16(a1, b0, acc[1][0], 0, 0, 0);
      acc[1][1] = __builtin_amdgcn_mfma_f32_16x16x32_bf16(a1, b1, acc[1][1], 0, 0, 0);
    }
  }
  int rbase = g * 4;
#pragma unroll
  for (int i = 0; i < 2; ++i)
#pragma unroll
    for (int j = 0; j < 2; ++j)
#pragma unroll
      for (int jj = 0; jj < 4; ++jj) {
        int row = m0 + wm + 16 * i + rbase + jj;  // m = b*512+s
        int cc  = n0 + wn + 16 * j + fr;          // n = h*64+d (or h*64+r)
        int b = row >> 9, s = row & 511, h = cc >> 6, d = cc & 63;
        unsigned short val = f2bf(acc[i][j][jj]);
        if (z == 0)      Qb[(((long)(b * 8 + h)) * 512 + s) * 64 + d] = val;
        else if (z == 1) Kb[(((long)(b * 8 + h)) * 512 + s) * 64 + d] = val;
        else if (z == 2) Vt[(((long)(b * 8 + h)) * 64 + d) * 512 + s] = val;
        else             QRb[(long)row * 512 + cc] = val;
      }
}

// K2: Sqkb[z] = A[z] @ B[z]^T, K=64 single stage, bf16 out. grid (4,4,32)
__global__ __launch_bounds__(256) void gemm128_c16(
    const unsigned short* __restrict__ Ag, const unsigned short* __restrict__ Bg,
    unsigned short* __restrict__ Cb) {
  int z = blockIdx.z;
  const unsigned short* A = Ag + (long)z * 32768;
  const unsigned short* Bm = Bg + (long)z * 32768;
  long coff = (long)z * 262144;
  int m0 = blockIdx.x * 128, n0 = blockIdx.y * 128;
  __shared__ alignas(16) unsigned short As[128 * 64];
  __shared__ alignas(16) unsigned short Bs[128 * 64];
  int t = threadIdx.x, lane = t & 63, w = t >> 6;
  int wm = (w >> 1) * 64, wn = (w & 1) * 64;
  int fr = lane & 15, g = lane >> 4;
  f32x4 acc[4][4] = {};
  G128_STAGE(As, A, 64, m0, 0)
  G128_STAGE(Bs, Bm, 64, n0, 0)
  __syncthreads();
  s16x8 af[2][4], bf_[2][4];
  G128_FRAGS(af, bf_)
#pragma unroll
  for (int kk = 0; kk < 2; ++kk)
#pragma unroll
    for (int i = 0; i < 4; ++i)
#pragma unroll
      for (int j = 0; j < 4; ++j)
        acc[i][j] = __builtin_amdgcn_mfma_f32_16x16x32_bf16(af[kk][i], bf_[kk][j],
                                                            acc[i][j], 0, 0, 0);
  int rbase = g * 4;
#pragma unroll
  for (int i = 0; i < 4; ++i)
#pragma unroll
    for (int j = 0; j < 4; ++j)
#pragma unroll
      for (int jj = 0; jj < 4; ++jj) {
        long row = m0 + wm + 16 * i + rbase + jj;
        int cc   = n0 + wn + 16 * j + fr;
        Cb[coff + row * 512 + cc] = f2bf(acc[i][j][jj]);
      }
}

// K4: out = P @ Vt^T per z; 32x64 m-tile, BK=64, gload_lds. grid (16,1,32)
__global__ __launch_bounds__(256) void gemm_pv(
    const unsigned short* __restrict__ Pg, const unsigned short* __restrict__ Vtg,
    float* __restrict__ out) {
  int z = blockIdx.z;  // b*8+h
  const unsigned short* A = Pg + (long)z * 262144;   // [512][512]
  const unsigned short* Bm = Vtg + (long)z * 32768;  // [64][512]
  long coff = (long)(z >> 3) * 262144 + (long)(z & 7) * 64;
  int m0 = blockIdx.x * 32;
  __shared__ alignas(16) unsigned short As[32 * 64];  // 4KB
  __shared__ alignas(16) unsigned short Bs[64 * 64];  // 8KB
  int t = threadIdx.x, lane = t & 63, w = t >> 6;
  int wm = (w >> 1) * 16, wn = (w & 1) * 32;
  int fr = lane & 15, g = lane >> 4;
  f32x4 acc[2] = {};
  for (int k0 = 0; k0 < 512; k0 += 64) {
    __syncthreads();
    {  // A tile: 256 chunks, 1/thread
      int fc = t, row = fc >> 3, cl = fc & 7;
      gload16(A + (long)(m0 + row) * 512 + k0 + ((cl ^ (row & 7)) * 8),
              (char*)As + (size_t)fc * 16);
    }
#pragma unroll
    for (int is = 0; is < 2; ++is) {  // B tile: 512 chunks, 2/thread
      int fc = is * 256 + t, row = fc >> 3, cl = fc & 7;
      gload16(Bm + (long)row * 512 + k0 + ((cl ^ (row & 7)) * 8),
              (char*)Bs + (size_t)fc * 16);
    }
    __syncthreads();
#pragma unroll
    for (int kh = 0; kh < 2; ++kh) {
      int ra = wm + fr;
      s16x8 a0 = *(const s16x8*)((const char*)As + ((size_t)ra * 8 + ((kh * 4 + g) ^ (ra & 7))) * 16);
      int rb0 = wn + fr, rb1 = wn + 16 + fr;
      s16x8 b0 = *(const s16x8*)((const char*)Bs + ((size_t)rb0 * 8 + ((kh * 4 + g) ^ (rb0 & 7))) * 16);
      s16x8 b1 = *(const s16x8*)((const char*)Bs + ((size_t)rb1 * 8 + ((kh * 4 + g) ^ (rb1 & 7))) * 16);
      acc[0] = __builtin_amdgcn_mfma_f32_16x16x32_bf16(a0, b0, acc[0], 0, 0, 0);
      acc[1] = __builtin_amdgcn_mfma_f32_16x16x32_bf16(a0, b1, acc[1], 0, 0, 0);
    }
  }
  int rbase = g * 4;
#pragma unroll
  for (int j = 0; j < 2; ++j)
#pragma unroll
    for (int jj = 0; jj < 4; ++jj) {
      long row = m0 + wm + rbase + jj;  // q
      int cc = wn + 16 * j + fr;        // d
      out[coff + row * 512 + cc] = acc[j][jj];
    }
}

// K3: per (b,q): compact active k; 2-deep pipelined rel stream; hoisted Sqk;
// s_lds init -8e9 encodes mask; s = (s_lds + Sqk)/8 ; softmax ; P bf16.
__global__ __launch_bounds__(256) void rel_fused(
    const float* __restrict__ rel, const int* __restrict__ graph,
    const unsigned short* __restrict__ Sqkb, const unsigned short* __restrict__ QRb,
    unsigned short* __restrict__ P) {
  int b = blockIdx.x >> 9, q = blockIdx.x & 511;
  __shared__ float s_lds[8][512];               // 16KB; -8e9 where masked
  __shared__ unsigned short qr16[16][64];       // 2KB
  __shared__ unsigned short idxL[512];          // 1KB
  __shared__ int cntL[8];
  int t = threadIdx.x, lane = t & 63, w = t >> 6;

  // init rel-score buffer to -8e9 (masked cols keep it -> logit ~ -1e9)
#pragma unroll
  for (int i = 0; i < 4; ++i) {
    f32x4 mv = {-8e9f, -8e9f, -8e9f, -8e9f};
    *(f32x4*)&s_lds[0][t * 4 + i * 1024] = mv;
  }
  // stage QR A-operand
  if (t < 64) {
    u16x8 v = *(const u16x8*)(QRb + ((long)(b * 512 + q)) * 512 + t * 8);
    *(u16x8*)&qr16[t >> 3][(t & 7) * 8] = v;
  } else if (t < 128) {
    u16x8 zv = {};
    *(u16x8*)&qr16[8 + ((t - 64) >> 3)][((t - 64) & 7) * 8] = zv;
  }
  // hoist Sqk softmax operands (only depend on b,q) -- issue early
  unsigned short sq[2][8];
#pragma unroll
  for (int hh = 0; hh < 2; ++hh) {
    int h = w + hh * 4;
    const unsigned short* srow = Sqkb + (((long)(b * 8 + h)) * 512 + q) * 512;
#pragma unroll
    for (int i = 0; i < 8; ++i) sq[hh][i] = srow[lane + 64 * i];
  }
  // ballot-compact active k (order irrelevant; idxL ends up ascending)
  const int* grow = graph + ((long)(b * 512 + q)) * 512;
  int gA = grow[t], gB = grow[t + 256];
  unsigned long long mA = __ballot(gA != 0);
  unsigned long long mB = __ballot(gB != 0);
  unsigned long long below = (lane == 63) ? ~0ull : ((1ull << (lane + 1)) - 1);
  below >>= 1;  // bits strictly below lane
  int pA = __popcll(mA & below), pB = __popcll(mB & below);
  if (lane == 0) { cntL[w] = __popcll(mA); cntL[4 + w] = __popcll(mB); }
  __syncthreads();
  int base[8];
  int nact = 0;
#pragma unroll
  for (int g2 = 0; g2 < 8; ++g2) { base[g2] = nact; nact += cntL[g2]; }
  if (gA) idxL[base[w] + pA] = (unsigned short)t;
  if (gB) idxL[base[4 + w] + pB] = (unsigned short)(t + 256);
  __syncthreads();

  int fr = lane & 15, fk = (lane >> 4) * 8;
  s16x8 aq0 = *(const s16x8*)&qr16[fr][fk];
  s16x8 aq1 = *(const s16x8*)&qr16[fr][32 + fk];
  const float* rg = rel + ((long)(b * 512 + q)) * 32768;
  int nchunk = (nact + 63) >> 6;

  // 2-deep pipelined chunk loop
  int slot_c = 16 * w + fr;
  int krow_c = (slot_c < nact) ? (int)idxL[slot_c] : 0;
  const float* rp0 = rg + krow_c * 64;
  f32x4 c0 = *(const f32x4*)(rp0 + fk);
  f32x4 c1 = *(const f32x4*)(rp0 + fk + 4);
  f32x4 c2 = *(const f32x4*)(rp0 + 32 + fk);
  f32x4 c3 = *(const f32x4*)(rp0 + 32 + fk + 4);
  for (int c = 0; c < nchunk; ++c) {
    int slot_n = (c + 1) * 64 + 16 * w + fr;
    int krow_n = (slot_n < nact) ? (int)idxL[slot_n] : 0;
    const float* rpn = rg + krow_n * 64;
    f32x4 n0 = *(const f32x4*)(rpn + fk);
    f32x4 n1 = *(const f32x4*)(rpn + fk + 4);
    f32x4 n2 = *(const f32x4*)(rpn + 32 + fk);
    f32x4 n3 = *(const f32x4*)(rpn + 32 + fk + 4);
    s16x8 b0, b1;
    b0[0] = (short)f2bf(c0.x); b0[1] = (short)f2bf(c0.y);
    b0[2] = (short)f2bf(c0.z); b0[3] = (short)f2bf(c0.w);
    b0[4] = (short)f2bf(c1.x); b0[5] = (short)f2bf(c1.y);
    b0[6] = (short)f2bf(c1.z); b0[7] = (short)f2bf(c1.w);
    b1[0] = (short)f2bf(c2.x); b1[1] = (short)f2bf(c2.y);
    b1[2] = (short)f2bf(c2.z); b1[3] = (short)f2bf(c2.w);
    b1[4] = (short)f2bf(c3.x); b1[5] = (short)f2bf(c3.y);
    b1[6] = (short)f2bf(c3.z); b1[7] = (short)f2bf(c3.w);
    f32x4 acc = {};
    acc = __builtin_amdgcn_mfma_f32_16x16x32_bf16(aq0, b0, acc, 0, 0, 0);
    acc = __builtin_amdgcn_mfma_f32_16x16x32_bf16(aq1, b1, acc, 0, 0, 0);
    if (lane < 32 && slot_c < nact) {  // C rows(h): row=(lane>>4)*4+j, col=krow_c
      int hb = (lane >> 4) * 4;
#pragma unroll
      for (int j = 0; j < 4; ++j) s_lds[hb + j][krow_c] = acc[j];
    }
    slot_c = slot_n; krow_c = krow_n;
    c0 = n0; c1 = n1; c2 = n2; c3 = n3;
  }
  __syncthreads();

  for (int hh = 0; hh < 2; ++hh) {  // wave w: rows h = w, w+4
    int h = w + hh * 4;
    float vals[8];
    float m = -3.0e38f;
#pragma unroll
    for (int i = 0; i < 8; ++i) {
      int k = lane + 64 * i;
      vals[i] = (s_lds[h][k] + bf2f(sq[hh][i])) * 0.125f;
      m = fmaxf(m, vals[i]);
    }
#pragma unroll
    for (int off = 32; off >= 1; off >>= 1) m = fmaxf(m, __shfl_xor(m, off));
    float sum = 0.f;
#pragma unroll
    for (int i = 0; i < 8; ++i) { vals[i] = __expf(vals[i] - m); sum += vals[i]; }
#pragma unroll
    for (int off = 32; off >= 1; off >>= 1) sum += __shfl_xor(sum, off);
    float inv = 1.0f / sum;
    unsigned short* Pg = P + (((long)(b * 8 + h)) * 512 + q) * 512;
#pragma unroll
    for (int i = 0; i < 8; ++i) Pg[lane + 64 * i] = f2bf(vals[i] * inv);
  }
}

extern "C" void kernel_launch(void* const* d_in, const int* in_sizes, int n_in,
                              void* d_out, int out_size, void* d_ws, size_t ws_size,
                              hipStream_t stream) {
  const float* x     = (const float*)d_in[0];
  const int*   graph = (const int*)d_in[1];
  const float* rel   = (const float*)d_in[2];
  const float* Wq    = (const float*)d_in[3];
  const float* Wk    = (const float*)d_in[4];
  const float* Wv    = (const float*)d_in[5];
  const float* Wr    = (const float*)d_in[6];
  float* out = (float*)d_out;

  char* wp = (char*)d_ws;
  unsigned short* xb  = (unsigned short*)wp; wp += (size_t)2 * 1048576;
  unsigned short* Wb  = (unsigned short*)wp; wp += (size_t)2 * 4 * 262144;
  unsigned short* Qb  = (unsigned short*)wp; wp += (size_t)2 * 1048576;
  unsigned short* Kb  = (unsigned short*)wp; wp += (size_t)2 * 1048576;
  unsigned short* Vt  = (unsigned short*)wp; wp += (size_t)2 * 1048576;
  unsigned short* QRb = (unsigned short*)wp; wp += (size_t)2 * 1048576;
  unsigned short* Sqkb = (unsigned short*)wp; wp += (size_t)2 * 8388608;
  unsigned short* P   = (unsigned short*)wp; wp += (size_t)2 * 8388608;

  prep<<<2816, 256, 0, stream>>>(x, Wq, Wk, Wv, Wr, xb, Wb);

  // Q/K/V/QR: M=2048, N=512, K=512, 4 batches, BK=128 gload_lds staging
  gemm_qkv_g<<<dim3(32, 8, 4), 256, 0, stream>>>(xb, Wb, Qb, Kb, Vt, QRb);

  // Sqk: M=N=512, K=64, 32 batches, bf16 out
  gemm128_c16<<<dim3(4, 4, 32), 256, 0, stream>>>(Qb, Kb, Sqkb);

  rel_fused<<<2048, 256, 0, stream>>>(rel, graph, Sqkb, QRb, P);

  // out = P @ Vt^T : M=512 (32-tiles), N=64, K=512, 32 batches, f32 out
  gemm_pv<<<dim3(16, 1, 32), 256, 0, stream>>>(P, Vt, out);
}